// Round 9
// baseline (164.105 us; speedup 1.0000x reference)
//
#include <hip/hip_runtime.h>

#define C_IN   64
#define C_OUT  128
#define Himg   128
#define Wimg   128
#define HW     (Himg * Wimg)
#define TROWS  16
#define TCOLS  32
#define HROWS  18   // TROWS+2
#define HCOLS  34   // TCOLS+2
#define XCELLS (HROWS * HCOLS)      // 612 pixel cells per k-group
#define XKSTR  (XCELLS * 16)        // 9792 B: Xs k-group stride

typedef __bf16 bf16x8 __attribute__((ext_vector_type(8)));
typedef float  f32x16 __attribute__((ext_vector_type(16)));

__device__ __forceinline__ unsigned int pack2(float a, float b) {
  union { __bf16 h; unsigned short s; } ua, ub;
  ua.h = (__bf16)a; ub.h = (__bf16)b;
  return (unsigned int)ua.s | ((unsigned int)ub.s << 16);
}

__device__ __forceinline__ void gload_lds16(const void* g, void* l) {
  __builtin_amdgcn_global_load_lds((const __attribute__((address_space(1))) void*)g,
                                   (__attribute__((address_space(3))) void*)l, 16, 0, 0);
}

// fp32 W[co][c][3][3] -> bf16 wt2, k-major 16B cells grouped by co-half:
// element index = ((coh*9 + tap)*8 + c/8)*512 + (co&63)*8 + (c&7)
// so a LINEAR global_load_lds of one coh-slice gives Ws[tap][kidx][co64] cells.
__global__ void wt_transform(const float* __restrict__ w, unsigned short* __restrict__ wt) {
  const int idx = blockIdx.x * 256 + threadIdx.x;
  if (idx >= 9 * C_OUT * C_IN) return;
  const int c   = idx & 63;
  const int co  = (idx >> 6) & 127;
  const int tap = idx >> 13;
  const int ky = tap / 3, kx = tap % 3;
  const float f = w[((co * C_IN + c) * 3 + ky) * 3 + kx];
  union { __bf16 h; unsigned short s; } u; u.h = (__bf16)f;
  const int coh = co >> 6, col = co & 63;
  wt[(((coh * 9 + tap) * 8) + (c >> 3)) * 512 + col * 8 + (c & 7)] = u.s;
}

__global__ __launch_bounds__(512, 1)
void conv_mfma(const float* __restrict__ xin, const unsigned short* __restrict__ wt,
               const float* __restrict__ bias, float* __restrict__ out) {
  __shared__ __align__(16) unsigned char Xs[8 * XKSTR];          // 78336: [kgrp][pixel] cells
  __shared__ __align__(16) unsigned char Ws[9 * 8 * 64 * 16];    // 73728: [tap][kidx][co64] cells

  const int tid = threadIdx.x;
  // bijective XCD swizzle: 2304 = 8 * 288
  const int wg  = (blockIdx.x & 7) * 288 + (blockIdx.x >> 3);
  const int coh = wg & 1;
  const int gx0 = ((wg >> 1) & 3) * TCOLS;
  const int gy0 = ((wg >> 3) & 7) * TROWS;
  const int img = wg >> 6;
  const int lane = tid & 63;
  const int wv   = tid >> 6;    // 0..7

  // ---- issue ALL Ws staging as async DMA (72 KB, 9 cells/thread); X staging covers latency ----
  {
    const unsigned short* wsrc = wt + coh * 36864 + tid * 8;
    #pragma unroll
    for (int j = 0; j < 9; ++j)
      gload_lds16(wsrc + j * 4096, &Ws[tid * 16 + j * 8192]);
  }

  // ---- stage X tile interior (fp32 -> bf16), storage pixel cols 1..32 ----
  {
    const int xi = tid & 31;                 // x offset within tile
    const int cq = tid >> 5;                 // 0..15 -> 4 channels each
    const int kg = cq >> 1;                  // k-group row
    const int bo = (cq & 1) * 8;             // half-cell byte offset
    const float* pbase = xin + ((size_t)img * C_IN + cq * 4) * HW + gx0 + xi;
    #pragma unroll
    for (int r = 0; r < HROWS; ++r) {
      const int gy = gy0 - 1 + r;
      float f0 = 0.f, f1 = 0.f, f2 = 0.f, f3 = 0.f;
      if (gy >= 0 && gy < Himg) {
        const float* p = pbase + (size_t)gy * Wimg;
        f0 = p[0];
        f1 = p[HW];
        f2 = p[2 * HW];
        f3 = p[3 * HW];
      }
      const int pix = r * HCOLS + 1 + xi;
      *(uint2*)(&Xs[kg * XKSTR + pix * 16 + bo]) = make_uint2(pack2(f0, f1), pack2(f2, f3));
    }
  }
  // ---- halo columns (pixel col 0 and 33): 2*18*64 = 2304 items ----
  for (int idx = tid; idx < 2 * HROWS * C_IN; idx += 512) {
    const int side = (idx >= HROWS * C_IN) ? 1 : 0;
    const int rem  = idx - side * HROWS * C_IN;
    const int c = rem & 63;
    const int r = rem >> 6;
    const int gy = gy0 - 1 + r;
    const int gx = side ? (gx0 + TCOLS) : (gx0 - 1);
    float f = 0.f;
    if (gy >= 0 && gy < Himg && gx >= 0 && gx < Wimg)
      f = xin[((size_t)img * C_IN + c) * HW + (size_t)gy * Wimg + gx];
    const int pix = r * HCOLS + (side ? (HCOLS - 1) : 0);
    union { __bf16 h; unsigned short s; } u; u.h = (__bf16)f;
    *(unsigned short*)(&Xs[(c >> 3) * XKSTR + pix * 16 + (c & 7) * 2]) = u.s;
  }

  // wave tile: 64 co x 64 px (rows wv*2, wv*2+1)
  const int lpx = lane & 31;
  const int lkh = lane >> 5;

  f32x16 acc[2][2];
  #pragma unroll
  for (int mf = 0; mf < 2; ++mf)
    #pragma unroll
    for (int nf = 0; nf < 2; ++nf)
      acc[mf][nf] = (f32x16)(0.f);

  // A cell: Ws[tap][ks*2+lkh][mf*32+lpx]   -> tap*8192 + ks*2048 + lkh*1024 + mf*512 + lpx*16
  // B cell: Xs[ks*2+lkh][row*34 + dx + lpx] -> (ks*2+lkh)*XKSTR + (...)*16
  const int abase = lkh * 1024 + lpx * 16;
  const int xbase = lkh * XKSTR + lpx * 16;

  __syncthreads();   // Xs + ALL Ws ready (drains DMA); read-only hereafter — no more barriers

  #pragma unroll
  for (int t = 0; t < 9; ++t) {
    const int dy = t / 3, dx = t % 3;
    int boff[2];
    #pragma unroll
    for (int nf = 0; nf < 2; ++nf)
      boff[nf] = xbase + ((wv * 2 + nf + dy) * HCOLS + dx) * 16;
    #pragma unroll
    for (int ks = 0; ks < 4; ++ks) {
      bf16x8 A0 = *(const bf16x8*)&Ws[abase + t * 8192 + ks * 2048];
      bf16x8 A1 = *(const bf16x8*)&Ws[abase + t * 8192 + ks * 2048 + 512];
      bf16x8 B0 = *(const bf16x8*)&Xs[boff[0] + ks * 2 * XKSTR];
      bf16x8 B1 = *(const bf16x8*)&Xs[boff[1] + ks * 2 * XKSTR];
      acc[0][0] = __builtin_amdgcn_mfma_f32_32x32x16_bf16(A0, B0, acc[0][0], 0, 0, 0);
      acc[0][1] = __builtin_amdgcn_mfma_f32_32x32x16_bf16(A0, B1, acc[0][1], 0, 0, 0);
      acc[1][0] = __builtin_amdgcn_mfma_f32_32x32x16_bf16(A1, B0, acc[1][0], 0, 0, 0);
      acc[1][1] = __builtin_amdgcn_mfma_f32_32x32x16_bf16(A1, B1, acc[1][1], 0, 0, 0);
    }
  }

  // ---- epilogue: bias + fp32 full-line stores ----
  float4 bq[2][4];
  #pragma unroll
  for (int mf = 0; mf < 2; ++mf)
    #pragma unroll
    for (int rq = 0; rq < 4; ++rq)
      bq[mf][rq] = *(const float4*)(bias + coh * 64 + mf * 32 + rq * 8 + lkh * 4);

  #pragma unroll
  for (int nf = 0; nf < 2; ++nf) {
    const int y = gy0 + wv * 2 + nf;
    float* op = out + (size_t)img * C_OUT * HW + (size_t)y * Wimg + gx0 + lpx;
    #pragma unroll
    for (int mf = 0; mf < 2; ++mf) {
      #pragma unroll
      for (int r = 0; r < 16; ++r) {
        const int co = coh * 64 + mf * 32 + (r & 3) + 8 * (r >> 2) + lkh * 4;
        op[(size_t)co * HW] = acc[mf][nf][r] + ((const float*)&bq[mf][r >> 2])[r & 3];
      }
    }
  }
}

extern "C" void kernel_launch(void* const* d_in, const int* in_sizes, int n_in,
                              void* d_out, int out_size, void* d_ws, size_t ws_size,
                              hipStream_t stream) {
  const float* x    = (const float*)d_in[0];
  const float* w    = (const float*)d_in[1];
  const float* bias = (const float*)d_in[2];
  float* out = (float*)d_out;
  unsigned short* wt = (unsigned short*)d_ws;  // 2*9*8*512 bf16 = 144 KB

  wt_transform<<<(9 * C_OUT * C_IN + 255) / 256, 256, 0, stream>>>(w, wt);

  conv_mfma<<<dim3(2304), 512, 0, stream>>>(x, wt, bias, out);
}